// Round 1
// baseline (18066.588 us; speedup 1.0000x reference)
//
#include <hip/hip_runtime.h>
#include <math.h>

// ---------------------------------------------------------------------------
// BiLSTM-CRF inference, fp32 everywhere (path output requires exact argmax
// reproduction; bf16/MFMA would flip Viterbi decisions).
//
// Pipeline (all on `stream`):
//   1. memset h-buffers to sentinel 0xFFFFFFFF (+ zero the two initial slots)
//   2. prep_w:   pack w_ih_f/w_ih_b -> [8192][544] (K padded 537->544), bias
//   3. charcnn:  char CNN + word-emb gather -> emb_pad [4096][544]
//   4. sgemm:    pre[4096][8192] = emb_pad @ w_pad^T + bias  (fp32, LDS-tiled)
//   5. lstm:     persistent kernel, 256 WGs (128 fwd + 128 bwd), weights in
//                VGPRs, sentinel-poll data-flow sync between WGs per step
//   6. tagproj:  feats[4096][12] = [hf|hb] @ w_tag^T + b_tag
//   7. viterbi:  single-block CRF forward (logsumexp) + shuffle backtrace
// ---------------------------------------------------------------------------

#define T_LEN 4096
#define NTAG 12
#define START_TAG 10
#define STOP_TAG 11
#define NEG_VAL (-10000.0f)
#define SENT 0xFFFFFFFFu

// workspace layout in floats
#define OF_EMB  0UL
#define OF_W    (OF_EMB + 4096UL * 544UL)          // emb_pad [4096][544]
#define OF_BIAS (OF_W + 8192UL * 544UL)            // w_pad   [8192][544]
#define OF_PRE  (OF_BIAS + 8192UL)                 // bias    [8192]
#define OF_HF   (OF_PRE + 4096UL * 8192UL)         // pre     [4096][8192]
#define OF_HB   (OF_HF + 4097UL * 1024UL)          // hf      [4097][1024]
#define OF_FEAT (OF_HB + 4097UL * 1024UL)          // hb      [4097][1024]
// feats [4096][12] ; total ~194.7 MB of d_ws

// ---------------------------------------------------------------------------
__global__ void prep_w_kernel(const float* __restrict__ wf, const float* __restrict__ wb,
                              const float* __restrict__ bif, const float* __restrict__ bhf,
                              const float* __restrict__ bib, const float* __restrict__ bhb,
                              float* __restrict__ wpad, float* __restrict__ bias) {
    int n = blockIdx.x;  // 0..8191
    const float* src = (n < 4096) ? (wf + (size_t)n * 537) : (wb + (size_t)(n - 4096) * 537);
    float* dst = wpad + (size_t)n * 544;
    for (int k = threadIdx.x; k < 544; k += blockDim.x)
        dst[k] = (k < 537) ? src[k] : 0.f;
    if (threadIdx.x == 0)
        bias[n] = (n < 4096) ? (bif[n] + bhf[n]) : (bib[n - 4096] + bhb[n - 4096]);
}

// ---------------------------------------------------------------------------
// char CNN (emb -> conv(3,25) pad(2,0) -> max over 22 positions) + word emb
__global__ void charcnn_kernel(const int* __restrict__ sentence, const int* __restrict__ chars,
                               const float* __restrict__ cemb, const float* __restrict__ cw,
                               const float* __restrict__ cb, const float* __restrict__ wemb,
                               float* __restrict__ emb) {
    int t = blockIdx.x, tid = threadIdx.x;
    __shared__ float ce[500];   // [20][25]
    __shared__ float yv[550];   // [25][22]
    for (int i = tid; i < 500; i += 256) {
        int c = chars[t * 20 + i / 25];
        ce[i] = cemb[c * 25 + i % 25];
    }
    __syncthreads();
    for (int i = tid; i < 550; i += 256) {
        int o = i / 22, p = i % 22;
        float v = cb[o];
        #pragma unroll
        for (int kh = 0; kh < 3; ++kh) {
            int ir = p - 2 + kh;  // zero padding of 2 on top/bottom
            if (ir >= 0 && ir < 20) {
                const float* crow = ce + ir * 25;
                const float* wrow = cw + o * 75 + kh * 25;
                #pragma unroll
                for (int kw = 0; kw < 25; ++kw) v = fmaf(crow[kw], wrow[kw], v);
            }
        }
        yv[o * 22 + p] = v;
    }
    __syncthreads();
    float* erow = emb + (size_t)t * 544;
    int sidx = sentence[t];
    if (tid < 128)  // word embedding copy, 128 x float4 = 512 floats
        ((float4*)erow)[tid] = ((const float4*)(wemb + (size_t)sidx * 512))[tid];
    if (tid >= 128 && tid < 153) {  // char features (25)
        int o = tid - 128;
        const float* yo = yv + o * 22;
        float m = yo[0];
        #pragma unroll
        for (int p = 1; p < 22; ++p) m = fmaxf(m, yo[p]);
        erow[512 + o] = m;
    }
    if (tid >= 160 && tid < 167) erow[537 + (tid - 160)] = 0.f;  // K padding
}

// ---------------------------------------------------------------------------
// fp32 GEMM: C[4096][8192] = A[4096][544] * B[8192][544]^T + bias
// 128x128 tile, BK=8, 256 threads, 8x8 micro-tile.
__global__ __launch_bounds__(256) void sgemm_kernel(const float* __restrict__ A,
                                                    const float* __restrict__ B,
                                                    const float* __restrict__ bias,
                                                    float* __restrict__ C) {
    __shared__ float As[8 * 128];
    __shared__ float Bs[8 * 128];
    const int tid = threadIdx.x;
    const int tx = tid & 15, ty = tid >> 4;
    const int t0 = blockIdx.y * 128, n0 = blockIdx.x * 128;
    const int r = tid >> 1, cq = tid & 1;
    const int rsw = r ^ (((r >> 5) & 3) << 2);  // bank swizzle for Bs
    float acc[8][8];
    #pragma unroll
    for (int i = 0; i < 8; ++i)
        #pragma unroll
        for (int j = 0; j < 8; ++j) acc[i][j] = 0.f;
    const float* Ap = A + (size_t)(t0 + r) * 544 + cq * 4;
    const float* Bp = B + (size_t)(n0 + r) * 544 + cq * 4;
    const int bsw = ((tx >> 2) & 3) << 2;
    for (int kt = 0; kt < 68; ++kt) {
        float4 av = *(const float4*)(Ap + kt * 8);
        float4 bv = *(const float4*)(Bp + kt * 8);
        __syncthreads();
        As[(cq * 4 + 0) * 128 + r] = av.x;
        As[(cq * 4 + 1) * 128 + r] = av.y;
        As[(cq * 4 + 2) * 128 + r] = av.z;
        As[(cq * 4 + 3) * 128 + r] = av.w;
        Bs[(cq * 4 + 0) * 128 + rsw] = bv.x;
        Bs[(cq * 4 + 1) * 128 + rsw] = bv.y;
        Bs[(cq * 4 + 2) * 128 + rsw] = bv.z;
        Bs[(cq * 4 + 3) * 128 + rsw] = bv.w;
        __syncthreads();
        #pragma unroll
        for (int k = 0; k < 8; ++k) {
            float a[8], b[8];
            #pragma unroll
            for (int i = 0; i < 8; ++i) a[i] = As[k * 128 + ty * 8 + i];
            #pragma unroll
            for (int j = 0; j < 8; ++j) b[j] = Bs[k * 128 + ((tx * 8 + j) ^ bsw)];
            #pragma unroll
            for (int i = 0; i < 8; ++i)
                #pragma unroll
                for (int j = 0; j < 8; ++j) acc[i][j] = fmaf(a[i], b[j], acc[i][j]);
        }
    }
    float bz[8];
    #pragma unroll
    for (int j = 0; j < 8; ++j) bz[j] = bias[n0 + tx * 8 + j];
    #pragma unroll
    for (int i = 0; i < 8; ++i) {
        float* crow = C + (size_t)(t0 + ty * 8 + i) * 8192 + n0 + tx * 8;
        float4 s0 = make_float4(acc[i][0] + bz[0], acc[i][1] + bz[1], acc[i][2] + bz[2], acc[i][3] + bz[3]);
        float4 s1 = make_float4(acc[i][4] + bz[4], acc[i][5] + bz[5], acc[i][6] + bz[6], acc[i][7] + bz[7]);
        ((float4*)crow)[0] = s0;
        ((float4*)crow)[1] = s1;
    }
}

// ---------------------------------------------------------------------------
// Persistent bidirectional LSTM. 256 WGs x 256 threads.
//   blocks 0..127   : forward,  WG w owns hidden units j0=w*8 .. j0+7
//   blocks 128..255 : backward
// Each WG keeps its 32 rows of w_hh (4 gates x 8 units x 1024) in VGPRs
// (128 floats/thread). Step sync: h buffers are pre-filled with the sentinel
// bit pattern 0xFFFFFFFF (a NaN, unreachable for h = o*tanh(c)); producers
// publish via relaxed agent-scope atomic stores, consumers spin on relaxed
// agent-scope atomic loads. Data IS the flag -> no fences needed.
__global__ __launch_bounds__(256) void lstm_kernel(const float* __restrict__ whhf,
                                                   const float* __restrict__ whhb,
                                                   const float* __restrict__ pre,
                                                   float* __restrict__ hfbuf,
                                                   float* __restrict__ hbbuf) {
    const int tid = threadIdx.x;
    const int dir = blockIdx.x >> 7;
    const int widx = blockIdx.x & 127;
    const int j0 = widx * 8;
    const int rr = tid >> 3, kk = tid & 7;   // row-local 0..31, k-slice 0..7
    const int g = rr >> 3, jj = rr & 7;      // gate 0..3, unit 0..7
    __shared__ float4 hlds[256];             // swizzled h vector (1024 floats)
    __shared__ float dots[32];
    __shared__ float pregs[32];

    // load this thread's 128 weights (row g*1024+j0+jj, cols kk*128..+127)
    const float* wsrc = (dir ? whhb : whhf) + (size_t)((g << 10) + j0 + jj) * 1024 + (kk << 7);
    float4 w[32];
    #pragma unroll
    for (int m = 0; m < 32; ++m) w[m] = ((const float4*)wsrc)[m];

    float* hbuf = dir ? hbbuf : hfbuf;
    unsigned* hbufu = (unsigned*)hbuf;
    const int dirofs = dir ? 4096 : 0;
    const int Gp = tid ^ ((tid >> 5) & 7);   // LDS bank swizzle (involution)
    float c = 0.f;

    for (int s = 0; s < T_LEN; ++s) {
        const int t = dir ? (T_LEN - 1 - s) : s;
        const int rdslot = dir ? (t + 1) : t;
        const int wrslot = dir ? t : (t + 1);

        // issue the input-projection load early (independent of the poll)
        float pg = 0.f;
        if (tid < 32)
            pg = pre[(size_t)t * 8192 + dirofs + ((tid >> 3) << 10) + j0 + (tid & 7)];

        // poll h_{prev}: 4 words per thread
        unsigned* hp = hbufu + ((size_t)rdslot << 10) + (tid << 2);
        unsigned v0 = __hip_atomic_load(hp + 0, __ATOMIC_RELAXED, __HIP_MEMORY_SCOPE_AGENT);
        unsigned v1 = __hip_atomic_load(hp + 1, __ATOMIC_RELAXED, __HIP_MEMORY_SCOPE_AGENT);
        unsigned v2 = __hip_atomic_load(hp + 2, __ATOMIC_RELAXED, __HIP_MEMORY_SCOPE_AGENT);
        unsigned v3 = __hip_atomic_load(hp + 3, __ATOMIC_RELAXED, __HIP_MEMORY_SCOPE_AGENT);
        while (v0 == SENT || v1 == SENT || v2 == SENT || v3 == SENT) {
            __builtin_amdgcn_s_sleep(1);
            if (v0 == SENT) v0 = __hip_atomic_load(hp + 0, __ATOMIC_RELAXED, __HIP_MEMORY_SCOPE_AGENT);
            if (v1 == SENT) v1 = __hip_atomic_load(hp + 1, __ATOMIC_RELAXED, __HIP_MEMORY_SCOPE_AGENT);
            if (v2 == SENT) v2 = __hip_atomic_load(hp + 2, __ATOMIC_RELAXED, __HIP_MEMORY_SCOPE_AGENT);
            if (v3 == SENT) v3 = __hip_atomic_load(hp + 3, __ATOMIC_RELAXED, __HIP_MEMORY_SCOPE_AGENT);
        }
        hlds[Gp] = make_float4(__uint_as_float(v0), __uint_as_float(v1),
                               __uint_as_float(v2), __uint_as_float(v3));
        __syncthreads();

        // dot: row rr, cols kk*128..+127 (h read swizzled: group kk*32+m -> ^kk)
        float acc = 0.f;
        #pragma unroll
        for (int m = 0; m < 32; ++m) {
            float4 hv = hlds[(kk << 5) + (m ^ kk)];
            acc = fmaf(w[m].x, hv.x, acc);
            acc = fmaf(w[m].y, hv.y, acc);
            acc = fmaf(w[m].z, hv.z, acc);
            acc = fmaf(w[m].w, hv.w, acc);
        }
        acc += __shfl_xor(acc, 1);
        acc += __shfl_xor(acc, 2);
        acc += __shfl_xor(acc, 4);
        if (kk == 0) dots[rr] = acc;
        if (tid < 32) pregs[tid] = pg;
        __syncthreads();

        // gates (pytorch order i,f,g,o), one thread per hidden unit
        if (tid < 8) {
            float iv = pregs[tid] + dots[tid];
            float fv = pregs[8 + tid] + dots[8 + tid];
            float gv = pregs[16 + tid] + dots[16 + tid];
            float ov = pregs[24 + tid] + dots[24 + tid];
            float ig = 1.f / (1.f + expf(-iv));
            float fg = 1.f / (1.f + expf(-fv));
            float gt = tanhf(gv);
            float og = 1.f / (1.f + expf(-ov));
            c = fg * c + ig * gt;
            float h = og * tanhf(c);
            __hip_atomic_store(hbufu + ((size_t)wrslot << 10) + j0 + tid, __float_as_uint(h),
                               __ATOMIC_RELAXED, __HIP_MEMORY_SCOPE_AGENT);
        }
        // no barrier needed here: next iteration's LDS writes are fenced by
        // the post-dot __syncthreads (gate threads pass it only after reads)
    }
}

// ---------------------------------------------------------------------------
// feats[t][tag] = [hf[t] | hb[t]] . w_tag[tag] + b_tag[tag]
__global__ __launch_bounds__(192) void tagproj_kernel(const float* __restrict__ hfbuf,
                                                      const float* __restrict__ hbbuf,
                                                      const float* __restrict__ wtag,
                                                      const float* __restrict__ btag,
                                                      float* __restrict__ feats) {
    int t = blockIdx.x, tid = threadIdx.x;
    __shared__ float hs[2048];
    for (int i = tid; i < 1024; i += 192) {
        hs[i] = hfbuf[((size_t)(t + 1) << 10) + i];
        hs[1024 + i] = hbbuf[((size_t)t << 10) + i];
    }
    __syncthreads();
    int tag = tid >> 4, sl = tid & 15;  // 12 tags x 16 slices
    float a = 0.f;
    const float* wrow = wtag + (size_t)tag * 2048;
    #pragma unroll 8
    for (int m = 0; m < 128; ++m) {
        int idx = (sl << 7) + ((m + sl * 9) & 127);  // phase-rotated to spread banks
        a = fmaf(hs[idx], wrow[idx], a);
    }
    a += __shfl_xor(a, 1);
    a += __shfl_xor(a, 2);
    a += __shfl_xor(a, 4);
    a += __shfl_xor(a, 8);
    if (sl == 0) feats[t * 12 + tag] = a + btag[tag];
}

// ---------------------------------------------------------------------------
// CRF forward (logsumexp) + argmax backpointers + backtrace, single block.
// Mirrors jax: smat = (alpha[:,None] + feat[None,:]) + trans; LSE/argmax axis 0.
__global__ __launch_bounds__(256) void viterbi_kernel(const float* __restrict__ feats,
                                                      const float* __restrict__ trans,
                                                      float* __restrict__ out) {
    const int tid = threadIdx.x;
    __shared__ float fbuf[256 * 12];
    __shared__ unsigned char bp[4096 * 12];
    float trf[12];
    float alpha = NEG_VAL;
    float tstop = 0.f;
    if (tid < 12) {
        #pragma unroll
        for (int f = 0; f < 12; ++f) trf[f] = trans[f * 12 + tid];
        if (tid == START_TAG) alpha = 0.f;
        tstop = trans[tid * 12 + STOP_TAG];
    }
    for (int ck = 0; ck < 16; ++ck) {
        __syncthreads();
        for (int i = tid; i < 3072; i += 256) fbuf[i] = feats[ck * 3072 + i];
        __syncthreads();
        if (tid < 12) {
            for (int tt = 0; tt < 256; ++tt) {
                float feat = fbuf[tt * 12 + tid];
                float sv[12];
                float m = -INFINITY;
                int best = 0;
                #pragma unroll
                for (int f = 0; f < 12; ++f) {
                    float af = __shfl(alpha, f);
                    float s = (af + feat) + trf[f];
                    sv[f] = s;
                    if (s > m) { m = s; best = f; }  // first-max wins (strict >)
                }
                float sum = 0.f;
                #pragma unroll
                for (int f = 0; f < 12; ++f) sum += expf(sv[f] - m);
                alpha = logf(sum) + m;
                bp[(ck * 256 + tt) * 12 + tid] = (unsigned char)best;
            }
        }
    }
    if (tid < 12) {
        float fin = alpha + tstop;
        float m = -INFINITY;
        int bl = 0;
        #pragma unroll
        for (int f = 0; f < 12; ++f) {
            float vf = __shfl(fin, f);
            if (vf > m) { m = vf; bl = f; }
        }
        float sum = 0.f;
        #pragma unroll
        for (int f = 0; f < 12; ++f) {
            float vf = __shfl(fin, f);
            sum += expf(vf - m);
        }
        float score = logf(sum) + m;
        if (tid == 0) {
            out[0] = score;            // output 0: score
            out[4096] = (float)bl;     // path[4095]
        }
        int cur = bl;
        for (int tt = 4095; tt >= 1; --tt) {
            int bv = (int)bp[tt * 12 + tid];
            cur = __shfl(bv, cur);     // path[tt-1] = bp[tt][path[tt]]
            if (tid == 0) out[tt] = (float)cur;
        }
    }
}

// ---------------------------------------------------------------------------
extern "C" void kernel_launch(void* const* d_in, const int* in_sizes, int n_in,
                              void* d_out, int out_size, void* d_ws, size_t ws_size,
                              hipStream_t stream) {
    (void)in_sizes; (void)n_in; (void)out_size; (void)ws_size;
    const int* sentence = (const int*)d_in[0];
    const int* chars = (const int*)d_in[1];
    // d_in[2] (caps) is unused by the reference forward
    const float* cemb = (const float*)d_in[3];
    const float* cw = (const float*)d_in[4];
    const float* cb = (const float*)d_in[5];
    const float* wemb = (const float*)d_in[6];
    const float* w_ih_f = (const float*)d_in[7];
    const float* w_hh_f = (const float*)d_in[8];
    const float* b_ih_f = (const float*)d_in[9];
    const float* b_hh_f = (const float*)d_in[10];
    const float* w_ih_b = (const float*)d_in[11];
    const float* w_hh_b = (const float*)d_in[12];
    const float* b_ih_b = (const float*)d_in[13];
    const float* b_hh_b = (const float*)d_in[14];
    const float* wtag = (const float*)d_in[15];
    const float* btag = (const float*)d_in[16];
    const float* trans = (const float*)d_in[17];

    float* ws = (float*)d_ws;
    float* emb = ws + OF_EMB;
    float* wpad = ws + OF_W;
    float* bias = ws + OF_BIAS;
    float* pre = ws + OF_PRE;
    float* hf = ws + OF_HF;
    float* hb = ws + OF_HB;
    float* feats = ws + OF_FEAT;

    // sentinel-fill h buffers, then zero the two initial-state slots
    hipMemsetAsync(hf, 0xFF, 4097UL * 1024UL * 4UL, stream);
    hipMemsetAsync(hb, 0xFF, 4097UL * 1024UL * 4UL, stream);
    hipMemsetAsync(hf, 0x00, 1024UL * 4UL, stream);                 // hf slot 0
    hipMemsetAsync(hb + 4096UL * 1024UL, 0x00, 1024UL * 4UL, stream);  // hb slot T

    hipLaunchKernelGGL(prep_w_kernel, dim3(8192), dim3(256), 0, stream,
                       w_ih_f, w_ih_b, b_ih_f, b_hh_f, b_ih_b, b_hh_b, wpad, bias);
    hipLaunchKernelGGL(charcnn_kernel, dim3(4096), dim3(256), 0, stream,
                       sentence, chars, cemb, cw, cb, wemb, emb);
    hipLaunchKernelGGL(sgemm_kernel, dim3(64, 32), dim3(256), 0, stream,
                       emb, wpad, bias, pre);
    hipLaunchKernelGGL(lstm_kernel, dim3(256), dim3(256), 0, stream,
                       w_hh_f, w_hh_b, pre, hf, hb);
    hipLaunchKernelGGL(tagproj_kernel, dim3(4096), dim3(192), 0, stream,
                       hf, hb, wtag, btag, feats);
    hipLaunchKernelGGL(viterbi_kernel, dim3(1), dim3(256), 0, stream,
                       feats, trans, (float*)d_out);
}